// Round 9
// baseline (159.535 us; speedup 1.0000x reference)
//
#include <hip/hip_runtime.h>

#define BB 8
#define TT 512
#define DD 512
#define LL 24
#define NBT (BB * TT)        // 4096 tokens
#define NWAVE (NBT * 2)      // 8192 waves: 2 waves per token, 12 levels each
#define NPART NWAVE

typedef float vf4 __attribute__((ext_vector_type(4)));

__global__ __launch_bounds__(256, 4) void hs_kernel(
    const float* __restrict__ x,
    const float* __restrict__ node_vecs,
    const int* __restrict__ paths,
    const int* __restrict__ codes,
    const int* __restrict__ mask,
    float* __restrict__ partials)
{
    const int tid  = threadIdx.x;
    const int lane = tid & 63;
    // scalarized wave index -> meta addresses provably wave-uniform -> s_load
    const int wave = __builtin_amdgcn_readfirstlane(tid >> 6);  // 0..3
    const int wid  = blockIdx.x * 4 + wave;                     // 0..8191
    const int bt   = wid >> 1;                                  // token
    const int lb   = bt * LL + (wid & 1) * 12;                  // first of this wave's 12 levels

    // ALL 12 levels' meta up front through the scalar cache
    int msk[12], cod[12], pth[12];
    #pragma unroll
    for (int l = 0; l < 12; ++l) {
        msk[l] = mask[lb + l];
        cod[l] = codes[lb + l];
        pth[l] = paths[lb + l];
    }

    // x row loaded ONCE per wave (in-register reuse across all 4 units)
    const vf4* xg = (const vf4*)(x + (size_t)bt * DD);
    const vf4 b0 = xg[lane];
    const vf4 b1 = xg[lane + 64];

    // double-buffered gather registers: unit i+1 issued before unit i consumed
    vf4 gA[2][3], gB[2][3];

    // prologue: issue unit 0 (levels 0..2)
    #pragma unroll
    for (int k = 0; k < 3; ++k) {
        if (msk[k]) {
            const vf4* nv = (const vf4*)(node_vecs + (size_t)pth[k] * DD);
            gA[0][k] = nv[lane];
            gB[0][k] = nv[lane + 64];
        } else { gA[0][k] = (vf4)(0.0f); gB[0][k] = (vf4)(0.0f); }
    }

    float local = 0.0f;
    #pragma unroll
    for (int i = 0; i < 4; ++i) {
        const int cb = i & 1, nb = cb ^ 1;

        // issue unit i+1's gathers BEFORE consuming unit i -> vmcnt(N) overlap
        if (i < 3) {
            #pragma unroll
            for (int k = 0; k < 3; ++k) {
                const int l = (i + 1) * 3 + k;
                if (msk[l]) {
                    const vf4* nv = (const vf4*)(node_vecs + (size_t)pth[l] * DD);
                    gA[nb][k] = nv[lane];
                    gB[nb][k] = nv[lane + 64];
                } else { gA[nb][k] = (vf4)(0.0f); gB[nb][k] = (vf4)(0.0f); }
            }
        }

        // consume unit i
        float dot[3];
        #pragma unroll
        for (int k = 0; k < 3; ++k) {
            dot[k] = gA[cb][k].x * b0.x + gA[cb][k].y * b0.y
                   + gA[cb][k].z * b0.z + gA[cb][k].w * b0.w
                   + gB[cb][k].x * b1.x + gB[cb][k].y * b1.y
                   + gB[cb][k].z * b1.z + gB[cb][k].w * b1.w;
        }
        #pragma unroll
        for (int off = 32; off >= 1; off >>= 1) {
            #pragma unroll
            for (int k = 0; k < 3; ++k)
                dot[k] += __shfl_xor(dot[k], off, 64);
        }
        #pragma unroll
        for (int k = 0; k < 3; ++k) {
            const int l = i * 3 + k;
            const float z   = (2.0f * (float)cod[l] - 1.0f) * dot[k];
            const float e   = __expf(-fabsf(z));                  // v_exp_f32
            const float nll = fmaxf(z, 0.0f) + __logf(1.0f + e);  // v_log_f32
            local += msk[l] ? nll : 0.0f;
        }
    }

    if (lane == 0) partials[wid] = local;
}

__global__ __launch_bounds__(1024) void hs_reduce(
    const float* __restrict__ partials, float* __restrict__ out)
{
    const int tid  = threadIdx.x;
    const int lane = tid & 63;
    const int wave = tid >> 6;          // 0..15
    __shared__ float wsum[16];

    const vf4* p4 = (const vf4*)partials;   // 2048 vf4s
    float s = 0.0f;
    #pragma unroll
    for (int r = 0; r < 2; ++r) {
        const vf4 v = p4[tid + r * 1024];
        s += (v.x + v.y) + (v.z + v.w);
    }

    #pragma unroll
    for (int off = 32; off >= 1; off >>= 1)
        s += __shfl_xor(s, off, 64);

    if (lane == 0) wsum[wave] = s;
    __syncthreads();
    if (tid == 0) {
        float t = 0.0f;
        #pragma unroll
        for (int i = 0; i < 16; ++i) t += wsum[i];
        out[0] = t * (1.0f / (float)BB);
    }
}

extern "C" void kernel_launch(void* const* d_in, const int* in_sizes, int n_in,
                              void* d_out, int out_size, void* d_ws, size_t ws_size,
                              hipStream_t stream) {
    const float* x         = (const float*)d_in[0];
    const float* node_vecs = (const float*)d_in[1];
    const int*   paths     = (const int*)d_in[2];
    const int*   codes     = (const int*)d_in[3];
    const int*   mask      = (const int*)d_in[4];
    float*       out       = (float*)d_out;
    float*       partials  = (float*)d_ws;   // 8192 floats = 32 KB, all written each launch

    hs_kernel<<<NWAVE / 4, 256, 0, stream>>>(x, node_vecs, paths, codes, mask, partials);
    hs_reduce<<<1, 1024, 0, stream>>>(partials, out);
}